// Round 1
// baseline (254.574 us; speedup 1.0000x reference)
//
#include <hip/hip_runtime.h>
#include <hip/hip_bf16.h>
#include <cstdint>
#include <cstddef>

// Problem constants (from reference): T=1024, H=1024, I=512, E=16, K=4
#define T_TOK 1024
#define HDIM  1024
#define IDIM  512
#define NEXP  16
#define TOPK  4

typedef __bf16 bf16;
typedef __attribute__((ext_vector_type(8))) __bf16 bf16x8;
typedef __attribute__((ext_vector_type(4))) __bf16 bf16x4;
typedef __attribute__((ext_vector_type(4))) float f32x4;

// async global->LDS, 16B per lane. LDS dest must be wave-uniform base + lane*16.
__device__ __forceinline__ void lds_load16(void* lds_dst, const void* g_src) {
  __builtin_amdgcn_global_load_lds(
      (__attribute__((address_space(1))) unsigned int*)(void*)(g_src),
      (__attribute__((address_space(3))) unsigned int*)(lds_dst),
      16, 0, 0);
}

// ---------------- prep kernels ----------------

__global__ void combine_kernel(const int* __restrict__ idx,
                               const float* __restrict__ w,
                               float* __restrict__ comb) {
  int t = blockIdx.x * blockDim.x + threadIdx.x;
  if (t >= T_TOK) return;
  float c[NEXP];
#pragma unroll
  for (int e = 0; e < NEXP; ++e) c[e] = 0.f;
#pragma unroll
  for (int k = 0; k < TOPK; ++k) {
    int ie = idx[t * TOPK + k];
    float wk = w[t * TOPK + k];
#pragma unroll
    for (int e = 0; e < NEXP; ++e) c[e] += (ie == e) ? wk : 0.f;
  }
#pragma unroll
  for (int e = 0; e < NEXP; ++e) comb[t * NEXP + e] = c[e];
}

__global__ void cvt_kernel(const float* __restrict__ src, bf16* __restrict__ dst, int n4) {
  int i = blockIdx.x * blockDim.x + threadIdx.x;
  if (i >= n4) return;
  float4 v = ((const float4*)src)[i];
  bf16x4 o;
  o[0] = (bf16)v.x; o[1] = (bf16)v.y; o[2] = (bf16)v.z; o[3] = (bf16)v.w;
  ((bf16x4*)dst)[i] = o;
}

// ---------------- GEMM1: gu = hidden @ gate_up[e].T, h_scaled = silu(g)*u*combine ----------------
// grid (T/128, I/128, E), block 256. Each block: 128 tokens x 128 intermediate channels,
// computing BOTH the gate tile (rows n0..) and up tile (rows I+n0..) of gate_up_proj[e].

template <bool BBF>
__global__ __launch_bounds__(256, 2) void gemm1_kernel(
    const bf16* __restrict__ hid,      // [T,H] bf16
    const float* __restrict__ gup_f,   // [E,2I,H] fp32 (fallback path)
    const bf16* __restrict__ gup_b,    // [E,2I,H] bf16 (big-ws path)
    const float* __restrict__ comb,    // [T,E]
    bf16* __restrict__ hsc) {          // [T, E*I] bf16
  __shared__ bf16 As[128 * 64];
  __shared__ bf16 Bg[128 * 64];
  __shared__ bf16 Bu[128 * 64];
  const int e  = blockIdx.z;
  const int m0 = blockIdx.x * 128;
  const int n0 = blockIdx.y * 128;
  const int tid  = threadIdx.x;
  const int lane = tid & 63;
  const int wm = ((tid >> 6) >> 1) * 64;   // wave's 64x64 sub-tile
  const int wn = ((tid >> 6) & 1) * 64;
  const int lcol = lane & 15;              // n (or m for A) index within frag
  const int lquad = lane >> 4;             // k-quad

  f32x4 accG[4][4], accU[4][4];
#pragma unroll
  for (int i = 0; i < 4; ++i)
#pragma unroll
    for (int j = 0; j < 4; ++j) {
      accG[i][j] = f32x4{0.f, 0.f, 0.f, 0.f};
      accU[i][j] = f32x4{0.f, 0.f, 0.f, 0.f};
    }

  const bf16* gA = hid + (size_t)(m0 + (tid >> 3)) * HDIM + (tid & 7) * 8;

  for (int kk = 0; kk < HDIM; kk += 64) {
    __syncthreads();
    // A tile: 128 rows x 64 cols bf16, async 16B/lane, 4 issues of 32 rows
#pragma unroll
    for (int i = 0; i < 4; ++i)
      lds_load16(&As[tid * 8 + i * 2048], gA + kk + (size_t)i * 32 * HDIM);
    if constexpr (BBF) {
      const bf16* gB = gup_b + (size_t)e * (2 * IDIM) * HDIM +
                       (size_t)(n0 + (tid >> 3)) * HDIM + (tid & 7) * 8 + kk;
#pragma unroll
      for (int i = 0; i < 4; ++i) {
        lds_load16(&Bg[tid * 8 + i * 2048], gB + (size_t)i * 32 * HDIM);
        lds_load16(&Bu[tid * 8 + i * 2048], gB + (size_t)IDIM * HDIM + (size_t)i * 32 * HDIM);
      }
    } else {
      const int r = tid >> 4;            // 16 rows per pass
      const int c4 = (tid & 15) * 4;     // float4 col
      const float* gB = gup_f + (size_t)e * (2 * IDIM) * HDIM +
                        (size_t)(n0 + r) * HDIM + kk + c4;
#pragma unroll
      for (int i = 0; i < 8; ++i) {
        float4 vg = *(const float4*)(gB + (size_t)i * 16 * HDIM);
        float4 vu = *(const float4*)(gB + (size_t)(IDIM + i * 16) * HDIM);
        bf16x4 og, ou;
        og[0] = (bf16)vg.x; og[1] = (bf16)vg.y; og[2] = (bf16)vg.z; og[3] = (bf16)vg.w;
        ou[0] = (bf16)vu.x; ou[1] = (bf16)vu.y; ou[2] = (bf16)vu.z; ou[3] = (bf16)vu.w;
        *(bf16x4*)&Bg[(r + i * 16) * 64 + c4] = og;
        *(bf16x4*)&Bu[(r + i * 16) * 64 + c4] = ou;
      }
    }
    __syncthreads();
#pragma unroll
    for (int ks = 0; ks < 2; ++ks) {
      bf16x8 af[4], bg[4], bu[4];
#pragma unroll
      for (int f = 0; f < 4; ++f) {
        af[f] = *(const bf16x8*)&As[(wm + f * 16 + lcol) * 64 + ks * 32 + lquad * 8];
        bg[f] = *(const bf16x8*)&Bg[(wn + f * 16 + lcol) * 64 + ks * 32 + lquad * 8];
        bu[f] = *(const bf16x8*)&Bu[(wn + f * 16 + lcol) * 64 + ks * 32 + lquad * 8];
      }
#pragma unroll
      for (int mf = 0; mf < 4; ++mf)
#pragma unroll
        for (int nf = 0; nf < 4; ++nf) {
          accG[mf][nf] = __builtin_amdgcn_mfma_f32_16x16x32_bf16(af[mf], bg[nf], accG[mf][nf], 0, 0, 0);
          accU[mf][nf] = __builtin_amdgcn_mfma_f32_16x16x32_bf16(af[mf], bu[nf], accU[mf][nf], 0, 0, 0);
        }
    }
  }
  // epilogue: C/D layout col=lane&15, row=quad*4+reg
#pragma unroll
  for (int mf = 0; mf < 4; ++mf) {
#pragma unroll
    for (int r = 0; r < 4; ++r) {
      const int tok = m0 + wm + mf * 16 + lquad * 4 + r;
      const float cmb = comb[tok * NEXP + e];
      bf16* orow = hsc + (size_t)tok * (NEXP * IDIM) + e * IDIM + n0 + wn;
#pragma unroll
      for (int nf = 0; nf < 4; ++nf) {
        float g = accG[mf][nf][r];
        float u = accU[mf][nf][r];
        float s = g / (1.f + __expf(-g));   // silu
        orow[nf * 16 + lcol] = (bf16)(s * u * cmb);
      }
    }
  }
}

// ---------------- GEMM2: out[t,h] += sum_i h_scaled[t,e*I+i] * down[e,h,i], split-K by expert ----------------
// grid (T/128, H/128, E), block 256, atomicAdd fp32 epilogue into zeroed d_out.

template <bool BBF>
__global__ __launch_bounds__(256, 3) void gemm2_kernel(
    const bf16* __restrict__ hsc,      // [T, E*I] bf16
    const float* __restrict__ down_f,  // [E,H,I] fp32 (fallback)
    const bf16* __restrict__ down_b,   // [E,H,I] bf16 (big-ws)
    float* __restrict__ out) {         // [T,H] fp32, pre-zeroed
  __shared__ bf16 As[128 * 64];
  __shared__ bf16 Bs[128 * 64];
  const int e  = blockIdx.z;
  const int m0 = blockIdx.x * 128;
  const int n0 = blockIdx.y * 128;
  const int tid  = threadIdx.x;
  const int lane = tid & 63;
  const int wm = ((tid >> 6) >> 1) * 64;
  const int wn = ((tid >> 6) & 1) * 64;
  const int lcol = lane & 15;
  const int lquad = lane >> 4;

  f32x4 acc[4][4];
#pragma unroll
  for (int i = 0; i < 4; ++i)
#pragma unroll
    for (int j = 0; j < 4; ++j) acc[i][j] = f32x4{0.f, 0.f, 0.f, 0.f};

  const bf16* gA = hsc + (size_t)(m0 + (tid >> 3)) * (NEXP * IDIM) + e * IDIM + (tid & 7) * 8;

  for (int kk = 0; kk < IDIM; kk += 64) {
    __syncthreads();
#pragma unroll
    for (int i = 0; i < 4; ++i)
      lds_load16(&As[tid * 8 + i * 2048], gA + kk + (size_t)i * 32 * (NEXP * IDIM));
    if constexpr (BBF) {
      const bf16* gB = down_b + (size_t)e * HDIM * IDIM +
                       (size_t)(n0 + (tid >> 3)) * IDIM + (tid & 7) * 8 + kk;
#pragma unroll
      for (int i = 0; i < 4; ++i)
        lds_load16(&Bs[tid * 8 + i * 2048], gB + (size_t)i * 32 * IDIM);
    } else {
      const int r = tid >> 4;
      const int c4 = (tid & 15) * 4;
      const float* gB = down_f + (size_t)e * HDIM * IDIM +
                        (size_t)(n0 + r) * IDIM + kk + c4;
#pragma unroll
      for (int i = 0; i < 8; ++i) {
        float4 v = *(const float4*)(gB + (size_t)i * 16 * IDIM);
        bf16x4 o;
        o[0] = (bf16)v.x; o[1] = (bf16)v.y; o[2] = (bf16)v.z; o[3] = (bf16)v.w;
        *(bf16x4*)&Bs[(r + i * 16) * 64 + c4] = o;
      }
    }
    __syncthreads();
#pragma unroll
    for (int ks = 0; ks < 2; ++ks) {
      bf16x8 af[4], bfv[4];
#pragma unroll
      for (int f = 0; f < 4; ++f) {
        af[f]  = *(const bf16x8*)&As[(wm + f * 16 + lcol) * 64 + ks * 32 + lquad * 8];
        bfv[f] = *(const bf16x8*)&Bs[(wn + f * 16 + lcol) * 64 + ks * 32 + lquad * 8];
      }
#pragma unroll
      for (int mf = 0; mf < 4; ++mf)
#pragma unroll
        for (int nf = 0; nf < 4; ++nf)
          acc[mf][nf] = __builtin_amdgcn_mfma_f32_16x16x32_bf16(af[mf], bfv[nf], acc[mf][nf], 0, 0, 0);
    }
  }
#pragma unroll
  for (int mf = 0; mf < 4; ++mf) {
#pragma unroll
    for (int r = 0; r < 4; ++r) {
      const int tok = m0 + wm + mf * 16 + lquad * 4 + r;
      float* orow = out + (size_t)tok * HDIM + n0 + wn;
#pragma unroll
      for (int nf = 0; nf < 4; ++nf)
        atomicAdd(&orow[nf * 16 + lcol], acc[mf][nf][r]);
    }
  }
}

// ---------------- launch ----------------

extern "C" void kernel_launch(void* const* d_in, const int* in_sizes, int n_in,
                              void* d_out, int out_size, void* d_ws, size_t ws_size,
                              hipStream_t stream) {
  const float* hid_f  = (const float*)d_in[0];
  const int*   idx    = (const int*)d_in[1];
  const float* tw     = (const float*)d_in[2];
  const float* gup_f  = (const float*)d_in[3];
  const float* down_f = (const float*)d_in[4];
  float* out = (float*)d_out;

  uint8_t* ws = (uint8_t*)d_ws;
  // ws layout: hid_bf16 (2MB) | combine (64KB) | h_scaled (16MB) | [gup_bf16 32MB | down_bf16 16MB]
  bf16*  hid_b = (bf16*)ws;
  size_t off = (size_t)T_TOK * HDIM * 2;
  float* comb = (float*)(ws + off);
  off += (size_t)T_TOK * NEXP * 4;
  bf16* hsc = (bf16*)(ws + off);
  off += (size_t)T_TOK * NEXP * IDIM * 2;
  bf16* gup_b = (bf16*)(ws + off);
  size_t gup_bytes = (size_t)NEXP * 2 * IDIM * HDIM * 2;
  bf16* down_b = (bf16*)(ws + off + gup_bytes);
  size_t need_big = off + gup_bytes + (size_t)NEXP * HDIM * IDIM * 2;
  const bool big = (ws_size >= need_big);

  hipMemsetAsync(d_out, 0, (size_t)T_TOK * HDIM * sizeof(float), stream);
  combine_kernel<<<dim3((T_TOK + 255) / 256), dim3(256), 0, stream>>>(idx, tw, comb);
  cvt_kernel<<<dim3(T_TOK * HDIM / 4 / 256), dim3(256), 0, stream>>>(hid_f, hid_b, T_TOK * HDIM / 4);

  if (big) {
    cvt_kernel<<<dim3(NEXP * 2 * IDIM * HDIM / 4 / 256), dim3(256), 0, stream>>>(
        gup_f, gup_b, NEXP * 2 * IDIM * HDIM / 4);
    cvt_kernel<<<dim3(NEXP * HDIM * IDIM / 4 / 256), dim3(256), 0, stream>>>(
        down_f, down_b, NEXP * HDIM * IDIM / 4);
    gemm1_kernel<true><<<dim3(T_TOK / 128, IDIM / 128, NEXP), dim3(256), 0, stream>>>(
        hid_b, nullptr, gup_b, comb, hsc);
    gemm2_kernel<true><<<dim3(T_TOK / 128, HDIM / 128, NEXP), dim3(256), 0, stream>>>(
        hsc, nullptr, down_b, out);
  } else {
    gemm1_kernel<false><<<dim3(T_TOK / 128, IDIM / 128, NEXP), dim3(256), 0, stream>>>(
        hid_b, gup_f, nullptr, comb, hsc);
    gemm2_kernel<false><<<dim3(T_TOK / 128, HDIM / 128, NEXP), dim3(256), 0, stream>>>(
        hsc, down_f, nullptr, out);
  }
}